// Round 12
// baseline (21.167 us; speedup 1.0000x reference)
//
#include <hip/hip_runtime.h>

// MedianFilter2D: 3x3 median, reflect pad, [16,3,512,512] f32.
// R11: R10 structure, single change — PLAIN stores instead of nontemporal.
// Working set (50MB in + 50MB out) is L3-resident; write-back stores let the
// output stream terminate in Infinity Cache instead of forcing the HBM write
// path every graph replay (NT `nt` flag bypasses L2/L3).
// Block = 512 cols x 32 out rows (two 16-row tiles, 34-row LDS, 69.6 KB):
//   stage A (18 rows, global_load_lds) -> vmcnt(0)+barrier
//   issue  B (16 rows, fire-and-forget) -> compute+store tile A
//   vmcnt(0)+barrier -> compute+store tile B.

constexpr int Wd = 512;
constexpr int Hd = 512;
constexpr int BR = 16;            // rows per tile
constexpr int SR = 2 * BR + 2;    // 34 staged rows per block

typedef float f32x4 __attribute__((ext_vector_type(4)));

__device__ __forceinline__ float med3f(float a, float b, float c) {
    return __builtin_amdgcn_fmed3f(a, b, c);
}
__device__ __forceinline__ float min3f(float a, float b, float c) {
    return fminf(fminf(a, b), c);   // v_min3_f32
}
__device__ __forceinline__ float max3f(float a, float b, float c) {
    return fmaxf(fmaxf(a, b), c);   // v_max3_f32
}

struct Trip { float mn[4], md[4], mx[4]; };

__global__ __launch_bounds__(256) void MedianFilter2D_68745246540291_kernel(
    const float* __restrict__ in, float* __restrict__ out) {
    __shared__ float lds[SR * Wd];          // 69,632 B

    int bid = blockIdx.x;
    int r0  = (bid & 15) * (2 * BR);        // 16 double-tiles per plane
    long plane = (long)(bid >> 4);

    const float* p = in  + plane * (long)(Hd * Wd);
    float*       q = out + plane * (long)(Hd * Wd);

    int tid  = threadIdx.x;
    int w    = tid >> 6;                    // wave id (0..3)
    int lane = tid & 63;

    // one chunk = half a row (256 floats = 1 KB); staged row s <- global row r0-1+s
    auto stage_chunk = [&](int c) {
        int s  = c >> 1;
        int hh = c & 1;
        int g  = r0 - 1 + s;
        int h  = (g < 0) ? 1 : ((g > Hd - 1) ? Hd - 2 : g);   // reflect rows
        const float* src = p + (long)h * Wd + hh * 256 + lane * 4;   // per-lane
        float* dst = &lds[s * Wd + hh * 256];                        // wave-uniform
        __builtin_amdgcn_global_load_lds(
            (const __attribute__((address_space(1))) void*)src,
            (__attribute__((address_space(3))) void*)dst, 16, 0, 0);
    };

    // ---- stage tile A: staged rows 0..17 (chunks 0..35)
#pragma unroll
    for (int k = 0; k < 9; ++k) stage_chunk(k * 4 + w);
    asm volatile("s_waitcnt vmcnt(0)" ::: "memory");
    __syncthreads();

    // ---- issue tile B stages: staged rows 18..33 (chunks 36..67), no wait
#pragma unroll
    for (int k = 0; k < 8; ++k) stage_chunk(36 + k * 4 + w);

    // ---- compute mapping: thread = 4-col group x 8 rows per tile
    int cg = tid & 127;
    int w4 = cg << 2;
    int rh = tid >> 7;                      // 0 or 1 (row half of tile)
    int lc = (w4 == 0)   ? 1   : w4 - 1;    // reflect col -1 -> 1
    int rc = (w4 == 508) ? 510 : w4 + 4;    // reflect col 512 -> 510

    auto mktrip = [&](int s) -> Trip {
        const float* row = &lds[s * Wd];
        f32x4 c4 = *reinterpret_cast<const f32x4*>(row + w4);
        float v[6] = { row[lc], c4.x, c4.y, c4.z, c4.w, row[rc] };
        Trip t;
#pragma unroll
        for (int j = 0; j < 4; ++j) {
            t.mn[j] = min3f(v[j], v[j + 1], v[j + 2]);
            t.md[j] = med3f(v[j], v[j + 1], v[j + 2]);
            t.mx[j] = max3f(v[j], v[j + 1], v[j + 2]);
        }
        return t;
    };
    // out row orow0+i uses staged rows sbase+i .. sbase+i+2
    auto compute_tile = [&](int sbase, int orow0) {
        Trip t0 = mktrip(sbase);
        Trip t1 = mktrip(sbase + 1);
#pragma unroll
        for (int i = 0; i < 8; ++i) {
            Trip t2 = mktrip(sbase + i + 2);
            f32x4 o;
#pragma unroll
            for (int j = 0; j < 4; ++j) {
                float lo = max3f(t0.mn[j], t1.mn[j], t2.mn[j]);
                float mi = med3f(t0.md[j], t1.md[j], t2.md[j]);
                float hi = min3f(t0.mx[j], t1.mx[j], t2.mx[j]);
                o[j] = med3f(lo, mi, hi);
            }
            *reinterpret_cast<f32x4*>(q + (long)(orow0 + i) * Wd + w4) = o;  // plain store
            t0 = t1;
            t1 = t2;
        }
    };

    // tile A (staged rows 0..17), overlapped with tile B's DMA
    compute_tile(rh * 8, r0 + rh * 8);

    asm volatile("s_waitcnt vmcnt(0)" ::: "memory");
    __syncthreads();

    // tile B (staged rows 16..33)
    compute_tile(16 + rh * 8, r0 + 16 + rh * 8);
}

extern "C" void kernel_launch(void* const* d_in, const int* in_sizes, int n_in,
                              void* d_out, int out_size, void* d_ws, size_t ws_size,
                              hipStream_t stream) {
    const float* in = (const float*)d_in[0];
    float* out = (float*)d_out;
    int grid = out_size / (Wd * 2 * BR);    // 768 blocks (48 planes x 16)
    MedianFilter2D_68745246540291_kernel<<<grid, 256, 0, stream>>>(in, out);
}

// Round 13
// 20.708 us; speedup vs baseline: 1.0222x; 1.0222x over previous
//
#include <hip/hip_runtime.h>

// MedianFilter2D: 3x3 median, reflect pad, [16,3,512,512] f32.
// FINAL (R10 structure, best measured: 20.79 us): cross-tile pipelined LDS
// staging via global_load_lds DMA + NT stores.
// Block = 512 cols x 32 out rows (two 16-row tiles, one 34-row LDS buffer,
// 69.6 KB, 2 blocks/CU):
//   stage A (18 rows, global_load_lds DMA) -> vmcnt(0)+barrier
//   issue  B (16 rows, fire-and-forget)    -> compute+NT-store tile A
//   vmcnt(0)+barrier                       -> compute+NT-store tile B
// Median: per-row horizontal sorted triple (min3/med3/max3), vertical
// med3(max3(mins), med3(meds), min3(maxs)) — exact, absmax 0.
// Traffic: 1.0625x read amp -> ~104 MB/call; measured ~5 TB/s effective
// (mixed read+write ceiling; pure streams run 6.6 TB/s on this chip).

constexpr int Wd = 512;
constexpr int Hd = 512;
constexpr int BR = 16;            // rows per tile
constexpr int SR = 2 * BR + 2;    // 34 staged rows per block

typedef float f32x4 __attribute__((ext_vector_type(4)));

__device__ __forceinline__ float med3f(float a, float b, float c) {
    return __builtin_amdgcn_fmed3f(a, b, c);
}
__device__ __forceinline__ float min3f(float a, float b, float c) {
    return fminf(fminf(a, b), c);   // v_min3_f32
}
__device__ __forceinline__ float max3f(float a, float b, float c) {
    return fmaxf(fmaxf(a, b), c);   // v_max3_f32
}

struct Trip { float mn[4], md[4], mx[4]; };

__global__ __launch_bounds__(256) void MedianFilter2D_68745246540291_kernel(
    const float* __restrict__ in, float* __restrict__ out) {
    __shared__ float lds[SR * Wd];          // 69,632 B

    int bid = blockIdx.x;
    int r0  = (bid & 15) * (2 * BR);        // 16 double-tiles per plane
    long plane = (long)(bid >> 4);

    const float* p = in  + plane * (long)(Hd * Wd);
    float*       q = out + plane * (long)(Hd * Wd);

    int tid  = threadIdx.x;
    int w    = tid >> 6;                    // wave id (0..3)
    int lane = tid & 63;

    // one chunk = half a row (256 floats = 1 KB); staged row s <- global row r0-1+s
    auto stage_chunk = [&](int c) {
        int s  = c >> 1;
        int hh = c & 1;
        int g  = r0 - 1 + s;
        int h  = (g < 0) ? 1 : ((g > Hd - 1) ? Hd - 2 : g);   // reflect rows
        const float* src = p + (long)h * Wd + hh * 256 + lane * 4;   // per-lane
        float* dst = &lds[s * Wd + hh * 256];                        // wave-uniform
        __builtin_amdgcn_global_load_lds(
            (const __attribute__((address_space(1))) void*)src,
            (__attribute__((address_space(3))) void*)dst, 16, 0, 0);
    };

    // ---- stage tile A: staged rows 0..17 (chunks 0..35)
#pragma unroll
    for (int k = 0; k < 9; ++k) stage_chunk(k * 4 + w);
    asm volatile("s_waitcnt vmcnt(0)" ::: "memory");
    __syncthreads();

    // ---- issue tile B stages: staged rows 18..33 (chunks 36..67), no wait
#pragma unroll
    for (int k = 0; k < 8; ++k) stage_chunk(36 + k * 4 + w);

    // ---- compute mapping: thread = 4-col group x 8 rows per tile
    int cg = tid & 127;
    int w4 = cg << 2;
    int rh = tid >> 7;                      // 0 or 1 (row half of tile)
    int lc = (w4 == 0)   ? 1   : w4 - 1;    // reflect col -1 -> 1
    int rc = (w4 == 508) ? 510 : w4 + 4;    // reflect col 512 -> 510

    auto mktrip = [&](int s) -> Trip {
        const float* row = &lds[s * Wd];
        f32x4 c4 = *reinterpret_cast<const f32x4*>(row + w4);
        float v[6] = { row[lc], c4.x, c4.y, c4.z, c4.w, row[rc] };
        Trip t;
#pragma unroll
        for (int j = 0; j < 4; ++j) {
            t.mn[j] = min3f(v[j], v[j + 1], v[j + 2]);
            t.md[j] = med3f(v[j], v[j + 1], v[j + 2]);
            t.mx[j] = max3f(v[j], v[j + 1], v[j + 2]);
        }
        return t;
    };
    // out row orow0+i uses staged rows sbase+i .. sbase+i+2
    auto compute_tile = [&](int sbase, int orow0) {
        Trip t0 = mktrip(sbase);
        Trip t1 = mktrip(sbase + 1);
#pragma unroll
        for (int i = 0; i < 8; ++i) {
            Trip t2 = mktrip(sbase + i + 2);
            f32x4 o;
#pragma unroll
            for (int j = 0; j < 4; ++j) {
                float lo = max3f(t0.mn[j], t1.mn[j], t2.mn[j]);
                float mi = med3f(t0.md[j], t1.md[j], t2.md[j]);
                float hi = min3f(t0.mx[j], t1.mx[j], t2.mx[j]);
                o[j] = med3f(lo, mi, hi);
            }
            __builtin_nontemporal_store(o, reinterpret_cast<f32x4*>(
                q + (long)(orow0 + i) * Wd + w4));
            t0 = t1;
            t1 = t2;
        }
    };

    // tile A (staged rows 0..17), overlapped with tile B's DMA
    compute_tile(rh * 8, r0 + rh * 8);

    asm volatile("s_waitcnt vmcnt(0)" ::: "memory");
    __syncthreads();

    // tile B (staged rows 16..33)
    compute_tile(16 + rh * 8, r0 + 16 + rh * 8);
}

extern "C" void kernel_launch(void* const* d_in, const int* in_sizes, int n_in,
                              void* d_out, int out_size, void* d_ws, size_t ws_size,
                              hipStream_t stream) {
    const float* in = (const float*)d_in[0];
    float* out = (float*)d_out;
    int grid = out_size / (Wd * 2 * BR);    // 768 blocks (48 planes x 16)
    MedianFilter2D_68745246540291_kernel<<<grid, 256, 0, stream>>>(in, out);
}